// Round 8
// baseline (344.535 us; speedup 1.0000x reference)
//
#include <hip/hip_runtime.h>
#include <math.h>

#define NBLK 256
#define BATCH 256
#define CLS 500
#define T_TEMP_ 10.0f
#define THRESH_ 0.86602540378443864676f
#define NEGV -9.0e15f
#define BAR_STRIDE 32   // u32s => 128 B per slot line

typedef __attribute__((ext_vector_type(8))) short short8;
typedef __attribute__((ext_vector_type(8))) unsigned short u16x8;
typedef __attribute__((ext_vector_type(4))) unsigned short u16x4;
typedef __attribute__((ext_vector_type(4))) float f32x4;
typedef __attribute__((ext_vector_type(2))) float f32x2;

static __device__ __forceinline__ unsigned short f2bf(float x) {
    unsigned int u = __builtin_bit_cast(unsigned int, x);
    u += 0x7fff + ((u >> 16) & 1);
    return (unsigned short)(u >> 16);
}
static __device__ __forceinline__ float bf2f(unsigned short v) {
    return __builtin_bit_cast(float, (unsigned int)v << 16);
}
static __device__ __forceinline__ u16x8 pack8(const float4& a, const float4& b) {
    u16x8 o;
    o[0] = f2bf(a.x); o[1] = f2bf(a.y); o[2] = f2bf(a.z); o[3] = f2bf(a.w);
    o[4] = f2bf(b.x); o[5] = f2bf(b.y); o[6] = f2bf(b.z); o[7] = f2bf(b.w);
    return o;
}

struct MegaP {
    const float *imgf, *attrs, *attg, *imgw, *semw, *semb, *fcw, *fcb;
    float* out;
    unsigned short *attr_bf, *imgf_bf, *attgT, *imgwT, *semwT, *gn_bf, *atto_bf, *hidP;
    float *gpart, *sim, *outP;
    unsigned int* bar;
};

// ---- RMW-free grid barrier: per-block flag lines + single go line ----
// slot[b] at st[b*BAR_STRIDE] (128B apart); go at st[256*BAR_STRIDE].
// Monotonic epochs k=1,2,...; state zeroed before launch.
static __device__ __forceinline__ void grid_barrier(unsigned int* st, unsigned int k) {
    __syncthreads();
    const int t = threadIdx.x;
    unsigned int* go = st + NBLK * BAR_STRIDE;
    if (blockIdx.x == 0) {
        if (t > 0) {   // thread t polls block t's slot (255 distinct lines, parallel)
            while (__hip_atomic_load(&st[t * BAR_STRIDE], __ATOMIC_ACQUIRE,
                                     __HIP_MEMORY_SCOPE_AGENT) < k)
                __builtin_amdgcn_s_sleep(1);
        }
        __syncthreads();
        if (t == 0) {
            __threadfence();
            __hip_atomic_store(go, k, __ATOMIC_RELEASE, __HIP_MEMORY_SCOPE_AGENT);
        }
    } else {
        if (t == 0) {
            __threadfence();
            __hip_atomic_store(&st[blockIdx.x * BAR_STRIDE], k, __ATOMIC_RELEASE,
                               __HIP_MEMORY_SCOPE_AGENT);
            while (__hip_atomic_load(go, __ATOMIC_ACQUIRE,
                                     __HIP_MEMORY_SCOPE_AGENT) < k)
                __builtin_amdgcn_s_sleep(4);
            __threadfence();
        }
        __syncthreads();
    }
}

// ---- bf16 MFMA GEMM tile (verbatim from round-5/7-verified code) ----
static __device__ __forceinline__ void gemm_tile(
    const unsigned short* __restrict__ A, int ar0, int alim,
    const unsigned short* __restrict__ B, int n0, int N,
    int K, int k0, int klen,
    float* __restrict__ Cf, unsigned short* __restrict__ Cbf, size_t coff,
    int M, int orow0base,
    unsigned short* AsP, unsigned short* BsP)
{
    const int t = threadIdx.x;
    const int w = t >> 6, lane = t & 63;
    const int wr = w >> 1, wc = w & 1;
    const int fr = lane & 15, kg = lane >> 4;
    const int a_row = t >> 2, a_k = (t & 3) * 8;
    const int b_row = t >> 1, b_k = (t & 1) * 16;
    const int gra = ar0 + a_row;
    const int grb = n0 + b_row;
    const bool va = gra < alim;
    const bool vb = grb < N;
    const size_t abase = (size_t)gra * K + a_k;
    const size_t bbase = (size_t)grb * K + b_k;

    u16x8 zz = {0,0,0,0,0,0,0,0};
    u16x8 pa = zz, pb0 = zz, pb1 = zz;
    if (va) pa = *(const u16x8*)&A[abase + k0];
    if (vb) { pb0 = *(const u16x8*)&B[bbase + k0]; pb1 = *(const u16x8*)&B[bbase + k0 + 8]; }

    f32x4 acc[2][4];
    #pragma unroll
    for (int i = 0; i < 2; ++i)
        #pragma unroll
        for (int j = 0; j < 4; ++j) acc[i][j] = (f32x4){0.f, 0.f, 0.f, 0.f};

    for (int kb = k0; kb < k0 + klen; kb += 32) {
        *(u16x8*)(AsP + a_row * 40 + a_k) = pa;
        *(u16x8*)(BsP + b_row * 40 + b_k) = pb0;
        *(u16x8*)(BsP + b_row * 40 + b_k + 8) = pb1;
        __syncthreads();

        const int kn = kb + 32;
        if (kn < k0 + klen) {
            if (va) pa = *(const u16x8*)&A[abase + kn];
            if (vb) { pb0 = *(const u16x8*)&B[bbase + kn]; pb1 = *(const u16x8*)&B[bbase + kn + 8]; }
        }

        short8 af[2], bfr[4];
        #pragma unroll
        for (int i = 0; i < 2; ++i)
            af[i] = *(short8*)(AsP + (wr * 32 + i * 16 + fr) * 40 + kg * 8);
        #pragma unroll
        for (int j = 0; j < 4; ++j)
            bfr[j] = *(short8*)(BsP + (wc * 64 + j * 16 + fr) * 40 + kg * 8);
        #pragma unroll
        for (int i = 0; i < 2; ++i)
            #pragma unroll
            for (int j = 0; j < 4; ++j)
                acc[i][j] = __builtin_amdgcn_mfma_f32_16x16x32_bf16(
                    af[i], bfr[j], acc[i][j], 0, 0, 0);
        __syncthreads();
    }

    const int orow0 = orow0base + wr * 32, ocol0 = n0 + wc * 64;
    if (Cbf) {
        unsigned short* Cw = Cbf + coff;
        #pragma unroll
        for (int i = 0; i < 2; ++i) {
            const int r0 = orow0 + i * 16 + kg * 4;
            #pragma unroll
            for (int j = 0; j < 4; ++j) {
                const int cc = ocol0 + j * 16 + fr;
                if (cc >= N) continue;
                #pragma unroll
                for (int r = 0; r < 4; ++r) {
                    const int rr = r0 + r;
                    if (rr < M) Cw[(size_t)rr * N + cc] = f2bf(acc[i][j][r]);
                }
            }
        }
    } else {
        float* Cw = Cf + coff;
        #pragma unroll
        for (int i = 0; i < 2; ++i) {
            const int r0 = orow0 + i * 16 + kg * 4;
            #pragma unroll
            for (int j = 0; j < 4; ++j) {
                const int cc = ocol0 + j * 16 + fr;
                if (cc >= N) continue;
                #pragma unroll
                for (int r = 0; r < 4; ++r) {
                    const int rr = r0 + r;
                    if (rr < M) Cw[(size_t)rr * N + cc] = acc[i][j][r];
                }
            }
        }
    }
}

__global__ __launch_bounds__(256) void mega_kernel(MegaP p)
{
    __shared__ __align__(16) char pool[35840];
    const int t = threadIdx.x;
    const int bid = blockIdx.x;
    unsigned short* As = (unsigned short*)pool;
    unsigned short* Bs = As + 64 * 40;

    // ================= P0: convert + transpose to bf16 =================
    for (int it = bid; it < 954; it += NBLK) {
        if (it < 378) {
            const float* s; unsigned short* d; int idx;
            if (it < 250) { s = p.attrs; d = p.attr_bf; idx = it * 2048 + t * 8; }
            else          { s = p.imgf;  d = p.imgf_bf; idx = (it - 250) * 2048 + t * 8; }
            float4 v0 = *(const float4*)&s[idx];
            float4 v1 = *(const float4*)&s[idx + 4];
            *(u16x8*)&d[idx] = pack8(v0, v1);
        } else {
            int b2 = it - 378;
            const float* s; unsigned short* d; int Csz;
            if (b2 < 64)       { s = p.attg; d = p.attgT; Csz = 256; }
            else if (b2 < 320) { b2 -= 64;  s = p.imgw; d = p.imgwT; Csz = 1024; }
            else               { b2 -= 320; s = p.semw; d = p.semwT; Csz = 1024; }
            const int tiles_c = Csz >> 6;
            const int tr = b2 / tiles_c, tc2 = b2 % tiles_c;
            unsigned short* tb = (unsigned short*)pool;
            __syncthreads();   // guard tb reuse across loop iterations
            {
                const int r = t >> 2, cq = (t & 3) * 16;
                const float* sp = &s[(size_t)(tr * 64 + r) * Csz + tc2 * 64 + cq];
                float4 v0 = *(const float4*)(sp);
                float4 v1 = *(const float4*)(sp + 4);
                float4 v2 = *(const float4*)(sp + 8);
                float4 v3 = *(const float4*)(sp + 12);
                *(u16x8*)&tb[r * 72 + cq]     = pack8(v0, v1);
                *(u16x8*)&tb[r * 72 + cq + 8] = pack8(v2, v3);
            }
            __syncthreads();
            {
                const int c = t >> 2, r0 = (t & 3) * 16;
                u16x8 o0, o1;
                #pragma unroll
                for (int i = 0; i < 8; ++i) { o0[i] = tb[(r0 + i) * 72 + c]; o1[i] = tb[(r0 + 8 + i) * 72 + c]; }
                unsigned short* q = &d[(size_t)(tc2 * 64 + c) * 1024 + tr * 64 + r0];
                *(u16x8*)q = o0;
                *(u16x8*)(q + 8) = o1;
            }
        }
    }
    grid_barrier(p.bar, 1);

    // ================= P1: g = attrs @ att_g^T  [500,256], split-K 16 =================
    {
        const int tile = bid >> 4, split = bid & 15;
        const int mt = tile >> 1, nt = tile & 1;
        gemm_tile(p.attr_bf, mt * 64, 500, p.attgT, nt * 128, 256,
                  1024, split * 64, 64,
                  p.gpart, nullptr, (size_t)split * (CLS * 256), 500, mt * 64, As, Bs);
    }
    grid_barrier(p.bar, 2);

    // ================= P2: reduce 16 partials + row-normalize -> gn bf16 =================
    if (bid < 250) {
        float* red = (float*)pool;
        for (int r = 0; r < 2; ++r) {
            const int c = bid * 2 + r;
            float v = 0.f;
            #pragma unroll
            for (int z = 0; z < 16; ++z) v += p.gpart[(size_t)z * (CLS * 256) + c * 256 + t];
            float ss = v * v;
            #pragma unroll
            for (int off = 32; off >= 1; off >>= 1) ss += __shfl_down(ss, off);
            const int wave = t >> 6, lane = t & 63;
            if (lane == 0) red[wave] = ss;
            __syncthreads();
            const float tot = red[0] + red[1] + red[2] + red[3];
            p.gn_bf[c * 256 + t] = f2bf(v * (1.f / sqrtf(tot)));
            __syncthreads();   // guard red reuse
        }
    }
    grid_barrier(p.bar, 3);

    // ================= P3: sim = gn @ gn^T  [500,500] =================
    if (bid < 32) {
        const int mt = bid >> 2, nt = bid & 3;
        gemm_tile(p.gn_bf, mt * 64, 500, p.gn_bf, nt * 128, 500,
                  256, 0, 256,
                  p.sim, nullptr, 0, 500, mt * 64, As, Bs);
    }
    grid_barrier(p.bar, 4);

    // ================= P4: masked softmax + sparse accumulate -> att_outs bf16 =================
    for (int c = bid; c < CLS; c += NBLK) {
        float* p_s  = (float*)pool;            // [512]
        float* redm = (float*)(pool + 2048);   // [4]
        float* reds = (float*)(pool + 2080);   // [4]

        const float d0 = p.sim[(size_t)c * CLS + t];
        const float d1 = (t + 256 < CLS) ? p.sim[(size_t)c * CLS + t + 256] : NEGV;

        float vmax = fmaxf((d0 > THRESH_) ? d0 : NEGV, (d1 > THRESH_) ? d1 : NEGV);
        #pragma unroll
        for (int off = 32; off >= 1; off >>= 1) vmax = fmaxf(vmax, __shfl_down(vmax, off));
        const int wave = t >> 6, lane = t & 63;
        if (lane == 0) redm[wave] = vmax;
        __syncthreads();
        const float m = fmaxf(fmaxf(redm[0], redm[1]), fmaxf(redm[2], redm[3]));

        const float p0 = (d0 > THRESH_) ? expf(T_TEMP_ * (d0 - m)) : 0.f;
        const float p1 = (d1 > THRESH_) ? expf(T_TEMP_ * (d1 - m)) : 0.f;
        p_s[t] = p0;
        p_s[t + 256] = p1;
        float vsum = p0 + p1;
        #pragma unroll
        for (int off = 32; off >= 1; off >>= 1) vsum += __shfl_down(vsum, off);
        if (lane == 0) reds[wave] = vsum;
        __syncthreads();
        const float inv = 1.f / (reds[0] + reds[1] + reds[2] + reds[3]);

        float acc[4] = {0.f, 0.f, 0.f, 0.f};
        for (int base = 0; base < 512; base += 64) {
            const float pv_l = p_s[base + lane];
            unsigned long long mask = __ballot(pv_l > 0.f);
            while (mask) {
                const int l = __ffsll((long long)mask) - 1;
                mask &= mask - 1;
                const int c2 = base + l;
                const float pv = p_s[c2];
                const float* ar = &p.attrs[(size_t)c2 * 1024 + t];
                #pragma unroll
                for (int j = 0; j < 4; ++j) acc[j] += pv * ar[256 * j];
            }
        }
        #pragma unroll
        for (int j = 0; j < 4; ++j)
            p.atto_bf[(size_t)c * 1024 + t + 256 * j] = f2bf(acc[j] * inv);
        __syncthreads();   // guard p_s reuse
    }
    grid_barrier(p.bar, 5);

    // ================= P5: hid[756,1024] bf16 partials, split-K 2 =================
    if (bid < 192) {
        const int tile = bid >> 1, split = bid & 1;
        const int mt = tile >> 3, nt = tile & 7;
        const unsigned short* A; const unsigned short* B; int ar0, alim;
        if (mt < 4) { A = p.imgf_bf; ar0 = mt * 64;       alim = 256; B = p.imgwT; }
        else        { A = p.atto_bf; ar0 = (mt - 4) * 64; alim = 500; B = p.semwT; }
        gemm_tile(A, ar0, alim, B, nt * 128, 1024,
                  1024, split * 512, 512,
                  nullptr, p.hidP, (size_t)split * (756 * 1024), 756, mt * 64, As, Bs);
    }
    grid_barrier(p.bar, 6);

    // ================= P6: fused relu-reduction -> outP[8][256][500] =================
    {
        const int bx = bid & 3, by = (bid >> 2) & 7, bz = bid >> 5;
        const int b0 = bx * 64, c0 = by * 64, h0 = bz * 128;
        float* imgs = (float*)pool;               // [64][68]
        float* sems = (float*)(pool + 17408);     // [64][68]
        float* fcs  = (float*)(pool + 34816);     // [128]
        const size_t pstride = (size_t)756 * 1024;
        const int tb_ = t >> 4, tc_ = t & 15;

        if (t < 32) *(f32x4*)&fcs[t * 4] = *(const f32x4*)&p.fcw[h0 + t * 4];

        f32x2 acc2[4][4];
        #pragma unroll
        for (int i = 0; i < 4; ++i)
            #pragma unroll
            for (int j = 0; j < 4; ++j) acc2[i][j] = (f32x2){0.f, 0.f};

        for (int hs = 0; hs < 2; ++hs) {
            const int hb = h0 + hs * 64;
            #pragma unroll
            for (int i = 0; i < 4; ++i) {
                const int row = (t >> 4) + 16 * i;
                const int col = (t & 15) * 4;
                f32x4 iv = {0.f, 0.f, 0.f, 0.f};
                const unsigned short* pi = &p.hidP[(size_t)(b0 + row) * 1024 + hb + col];
                #pragma unroll
                for (int z = 0; z < 2; ++z) {
                    u16x4 vz = *(const u16x4*)(pi + (size_t)z * pstride);
                    iv[0] += bf2f(vz[0]); iv[1] += bf2f(vz[1]);
                    iv[2] += bf2f(vz[2]); iv[3] += bf2f(vz[3]);
                }
                *(f32x4*)&imgs[row * 68 + col] = iv;

                f32x4 sv = {0.f, 0.f, 0.f, 0.f};
                if (c0 + row < CLS) {
                    const unsigned short* ps2 = &p.hidP[(size_t)(256 + c0 + row) * 1024 + hb + col];
                    #pragma unroll
                    for (int z = 0; z < 2; ++z) {
                        u16x4 vz = *(const u16x4*)(ps2 + (size_t)z * pstride);
                        sv[0] += bf2f(vz[0]); sv[1] += bf2f(vz[1]);
                        sv[2] += bf2f(vz[2]); sv[3] += bf2f(vz[3]);
                    }
                    const f32x4 bb = *(const f32x4*)&p.semb[hb + col];
                    sv += bb;
                }
                *(f32x4*)&sems[row * 68 + col] = sv;
            }
            __syncthreads();

            #pragma unroll
            for (int h4 = 0; h4 < 16; ++h4) {
                f32x4 ia[4], sa[4];
                #pragma unroll
                for (int i = 0; i < 4; ++i) ia[i] = *(f32x4*)&imgs[(tb_ + 16 * i) * 68 + h4 * 4];
                #pragma unroll
                for (int j = 0; j < 4; ++j) sa[j] = *(f32x4*)&sems[(tc_ + 16 * j) * 68 + h4 * 4];
                const f32x4 wv = *(const f32x4*)&fcs[hs * 64 + h4 * 4];
                #pragma unroll
                for (int e2 = 0; e2 < 2; ++e2) {
                    const f32x2 w2 = {wv[2 * e2], wv[2 * e2 + 1]};
                    f32x2 ia2[4], sa2[4];
                    #pragma unroll
                    for (int i = 0; i < 4; ++i) ia2[i] = (f32x2){ia[i][2 * e2], ia[i][2 * e2 + 1]};
                    #pragma unroll
                    for (int j = 0; j < 4; ++j) sa2[j] = (f32x2){sa[j][2 * e2], sa[j][2 * e2 + 1]};
                    #pragma unroll
                    for (int i = 0; i < 4; ++i)
                        #pragma unroll
                        for (int j = 0; j < 4; ++j) {
                            f32x2 s = ia2[i] + sa2[j];
                            s = __builtin_elementwise_max(s, (f32x2){0.f, 0.f});
                            acc2[i][j] += s * w2;
                        }
                }
            }
            __syncthreads();
        }

        #pragma unroll
        for (int i = 0; i < 4; ++i) {
            const int b = b0 + tb_ + 16 * i;
            #pragma unroll
            for (int j = 0; j < 4; ++j) {
                const int cc = c0 + tc_ + 16 * j;
                if (cc < CLS)
                    p.outP[((size_t)bz * BATCH + b) * CLS + cc] = acc2[i][j][0] + acc2[i][j][1];
            }
        }
    }
    grid_barrier(p.bar, 7);

    // ================= P7: finalize =================
    {
        int idx = bid * 256 + t;
        #pragma unroll
        for (int r = 0; r < 2; ++r, idx += 65536) {
            if (idx < BATCH * CLS) {
                float s = p.fcb[0];
                #pragma unroll
                for (int nh = 0; nh < 8; ++nh)
                    s += p.outP[(size_t)nh * (BATCH * CLS) + idx];
                p.out[idx] = s;
            }
        }
    }
}

extern "C" void kernel_launch(void* const* d_in, const int* in_sizes, int n_in,
                              void* d_out, int out_size, void* d_ws, size_t ws_size,
                              hipStream_t stream)
{
    MegaP P;
    P.imgf  = (const float*)d_in[0];
    P.attrs = (const float*)d_in[1];
    P.attg  = (const float*)d_in[3];
    P.imgw  = (const float*)d_in[4];
    P.semw  = (const float*)d_in[5];
    P.semb  = (const float*)d_in[6];
    P.fcw   = (const float*)d_in[7];
    P.fcb   = (const float*)d_in[8];
    P.out   = (float*)d_out;

    char* ws = (char*)d_ws;
    // barrier state: 256 slot lines (128 B each) + go line = 33024 B
    const size_t bar_bytes = (size_t)NBLK * BAR_STRIDE * 4 + 128;
    size_t off = 33280;
    auto alloc = [&](size_t b) { size_t o = off; off = (off + b + 255) & ~(size_t)255; return o; };

    P.bar     = (unsigned int*)ws;
    P.attr_bf = (unsigned short*)(ws + alloc((size_t)500 * 1024 * 2));
    P.imgf_bf = (unsigned short*)(ws + alloc((size_t)256 * 1024 * 2));
    P.attgT   = (unsigned short*)(ws + alloc((size_t)256 * 1024 * 2));
    P.imgwT   = (unsigned short*)(ws + alloc((size_t)1024 * 1024 * 2));
    P.semwT   = (unsigned short*)(ws + alloc((size_t)1024 * 1024 * 2));
    P.gn_bf   = (unsigned short*)(ws + alloc((size_t)500 * 256 * 2));
    P.atto_bf = (unsigned short*)(ws + alloc((size_t)500 * 1024 * 2));
    P.hidP    = (unsigned short*)(ws + alloc((size_t)2 * 756 * 1024 * 2));
    P.gpart   = (float*)(ws + alloc((size_t)16 * CLS * 256 * 4));
    P.sim     = (float*)(ws + alloc((size_t)CLS * CLS * 4));
    P.outP    = (float*)(ws + alloc((size_t)8 * BATCH * CLS * 4));

    // zero the grid-barrier state (captured into the graph; runs every replay)
    hipMemsetAsync(d_ws, 0, bar_bytes, stream);
    mega_kernel<<<NBLK, 256, 0, stream>>>(P);
}

// Round 9
// 74.800 us; speedup vs baseline: 4.6061x; 4.6061x over previous
//
#include <hip/hip_runtime.h>
#include <math.h>

#define BATCH 256
#define CLS 500
#define T_TEMP_ 10.0f
#define THRESH_ 0.86602540378443864676f
#define NEGV -9.0e15f

typedef __attribute__((ext_vector_type(8))) short short8;
typedef __attribute__((ext_vector_type(8))) unsigned short u16x8;
typedef __attribute__((ext_vector_type(4))) unsigned short u16x4;
typedef __attribute__((ext_vector_type(4))) float f32x4;
typedef __attribute__((ext_vector_type(2))) float f32x2;

static __device__ __forceinline__ unsigned short f2bf(float x) {
    unsigned int u = __builtin_bit_cast(unsigned int, x);
    u += 0x7fff + ((u >> 16) & 1);
    return (unsigned short)(u >> 16);
}
static __device__ __forceinline__ float bf2f(unsigned short v) {
    return __builtin_bit_cast(float, (unsigned int)v << 16);
}
static __device__ __forceinline__ float fel(const float4& v, int j) { return (&v.x)[j]; }
static __device__ __forceinline__ u16x8 pack8(const float4& a, const float4& b) {
    u16x8 o;
    o[0] = f2bf(a.x); o[1] = f2bf(a.y); o[2] = f2bf(a.z); o[3] = f2bf(a.w);
    o[4] = f2bf(b.x); o[5] = f2bf(b.y); o[6] = f2bf(b.z); o[7] = f2bf(b.w);
    return o;
}

// =============== K1: g = attrs @ att_g (inline f32->bf16) + group reduce+norm ===============
// grid 128: mt = bid>>4 (8 m-tiles), nt = (bid>>3)&1, split = bid&7 (klen=128).
// Partials -> gpart[8][512][256] via agent(sc1) stores; per-mt group of 16 syncs on a
// counter (no fences -- sc1 data is coherent), then cooperatively reduces+normalizes.
__global__ __launch_bounds__(256) void g_norm_kernel(
    const float* __restrict__ attrs, const float* __restrict__ attg,
    float* __restrict__ gpart, unsigned short* __restrict__ gn_bf,
    unsigned int* __restrict__ cnt)
{
    __shared__ unsigned short As[64][40];
    __shared__ unsigned short Bs[128][40];
    __shared__ float red[4];
    __shared__ unsigned int rank_s;
    const int t = threadIdx.x;
    const int bid = blockIdx.x;
    const int mt = bid >> 4, nt = (bid >> 3) & 1, split = bid & 7;
    const int n0 = nt * 128, ar0 = mt * 64, k0 = split * 128;

    const int w = t >> 6, lane = t & 63;
    const int wr = w >> 1, wc = w & 1;
    const int fr = lane & 15, kg = lane >> 4;
    const int as_row = t >> 2, as_kq = t & 3;
    const int bs_nc = (t & 31) * 4, bs_kr = t >> 5;

    f32x4 acc[2][4];
    #pragma unroll
    for (int i = 0; i < 2; ++i)
        #pragma unroll
        for (int j = 0; j < 4; ++j) acc[i][j] = (f32x4){0.f, 0.f, 0.f, 0.f};

    for (int kb = k0; kb < k0 + 128; kb += 32) {
        {   // A stage: attrs f32 -> bf16 (round-4-verified pattern)
            const int gr = ar0 + as_row;
            float4 v0 = make_float4(0.f,0.f,0.f,0.f), v1 = v0;
            if (gr < CLS) {
                const float* ap = &attrs[(size_t)gr * 1024 + kb + as_kq * 8];
                v0 = *(const float4*)ap; v1 = *(const float4*)(ap + 4);
            }
            *(u16x8*)&As[as_row][as_kq * 8] = pack8(v0, v1);
        }
        {   // B stage: attg f32 [K=1024][N=256] row-major -> Bs[n][k] (round-4-verified)
            const float* bp = &attg[(size_t)(kb + bs_kr * 4) * 256 + n0 + bs_nc];
            float4 r0 = *(const float4*)(bp);
            float4 r1 = *(const float4*)(bp + 256);
            float4 r2 = *(const float4*)(bp + 512);
            float4 r3 = *(const float4*)(bp + 768);
            #pragma unroll
            for (int j = 0; j < 4; ++j) {
                unsigned int lo = (unsigned int)f2bf(fel(r0, j)) | ((unsigned int)f2bf(fel(r1, j)) << 16);
                unsigned int hi = (unsigned int)f2bf(fel(r2, j)) | ((unsigned int)f2bf(fel(r3, j)) << 16);
                uint2 u2; u2.x = lo; u2.y = hi;
                *(uint2*)&Bs[bs_nc + j][bs_kr * 4] = u2;
            }
        }
        __syncthreads();
        short8 af[2], bfr[4];
        #pragma unroll
        for (int i = 0; i < 2; ++i) af[i] = *(short8*)&As[wr * 32 + i * 16 + fr][kg * 8];
        #pragma unroll
        for (int j = 0; j < 4; ++j) bfr[j] = *(short8*)&Bs[wc * 64 + j * 16 + fr][kg * 8];
        #pragma unroll
        for (int i = 0; i < 2; ++i)
            #pragma unroll
            for (int j = 0; j < 4; ++j)
                acc[i][j] = __builtin_amdgcn_mfma_f32_16x16x32_bf16(af[i], bfr[j], acc[i][j], 0, 0, 0);
        __syncthreads();
    }

    // epilogue: agent-coherent scalar stores (bypass L2-dirty -> no fence needed)
    float* Gp = gpart + (size_t)split * (512 * 256);
    const int orow0 = ar0 + wr * 32, ocol0 = n0 + wc * 64;
    #pragma unroll
    for (int i = 0; i < 2; ++i) {
        const int r0 = orow0 + i * 16 + kg * 4;
        #pragma unroll
        for (int j = 0; j < 4; ++j) {
            const int cc = ocol0 + j * 16 + fr;
            #pragma unroll
            for (int r = 0; r < 4; ++r)
                __hip_atomic_store(&Gp[(size_t)(r0 + r) * 256 + cc], acc[i][j][r],
                                   __ATOMIC_RELAXED, __HIP_MEMORY_SCOPE_AGENT);
        }
    }
    asm volatile("s_waitcnt vmcnt(0)" ::: "memory");   // per-wave drain of sc1 stores
    __syncthreads();                                    // => whole block drained
    if (t == 0) {
        rank_s = __hip_atomic_fetch_add(&cnt[mt * 32], 1u, __ATOMIC_RELAXED,
                                        __HIP_MEMORY_SCOPE_AGENT);
        while (__hip_atomic_load(&cnt[mt * 32], __ATOMIC_RELAXED,
                                 __HIP_MEMORY_SCOPE_AGENT) < 16u)
            __builtin_amdgcn_s_sleep(1);
    }
    __syncthreads();
    const int rank = (int)rank_s;   // 0..15, unique within group

    // cooperative reduce + normalize: 4 rows per block (fixed z-order -> deterministic)
    #pragma unroll
    for (int rr4 = 0; rr4 < 4; ++rr4) {
        const int r = mt * 64 + rank * 4 + rr4;   // block-uniform
        if (r < CLS) {
            float v = 0.f;
            #pragma unroll
            for (int z = 0; z < 8; ++z)
                v += gpart[(size_t)z * (512 * 256) + (size_t)r * 256 + t];
            float ss = v * v;
            #pragma unroll
            for (int off = 32; off >= 1; off >>= 1) ss += __shfl_down(ss, off);
            if (lane == 0) red[w] = ss;
            __syncthreads();
            const float tot = red[0] + red[1] + red[2] + red[3];
            gn_bf[r * 256 + t] = f2bf(v * (1.f / sqrtf(tot)));
            __syncthreads();
        }
    }
}

// =============== K3: sim = gn @ gn^T (round-5-verified kernel, verbatim) ===============
__global__ __launch_bounds__(256) void mfma_gemm_bf(
    const unsigned short* __restrict__ A1, int alim1,
    const unsigned short* __restrict__ A2, int a2t0, int alim2,
    const unsigned short* __restrict__ B1, const unsigned short* __restrict__ B2,
    float* __restrict__ C, unsigned short* __restrict__ Cbf,
    int M, int N, int K, int klen)
{
    __shared__ unsigned short As[64][40];
    __shared__ unsigned short Bs[128][40];

    const int t  = threadIdx.x;
    const int bx = blockIdx.x;
    const int n0 = blockIdx.y * 128;
    const int k0 = blockIdx.z * klen;

    const unsigned short* A; const unsigned short* B; int ar0, alim;
    if (bx < a2t0) { A = A1; B = B1; ar0 = bx * 64;          alim = alim1; }
    else           { A = A2; B = B2; ar0 = (bx - a2t0) * 64; alim = alim2; }

    const int w = t >> 6, lane = t & 63;
    const int wr = w >> 1, wc = w & 1;
    const int fr = lane & 15, kg = lane >> 4;

    const int a_row = t >> 2, a_k = (t & 3) * 8;
    const int b_row = t >> 1, b_k = (t & 1) * 16;
    const int gra = ar0 + a_row;
    const int grb = n0 + b_row;
    const bool va = gra < alim;
    const bool vb = grb < N;
    const size_t abase = (size_t)gra * K + a_k;
    const size_t bbase = (size_t)grb * K + b_k;

    u16x8 zz = {0,0,0,0,0,0,0,0};
    u16x8 pa = zz, pb0 = zz, pb1 = zz;
    if (va) pa = *(const u16x8*)&A1[abase + k0];
    if (vb) { pb0 = *(const u16x8*)&B1[bbase + k0]; pb1 = *(const u16x8*)&B1[bbase + k0 + 8]; }

    f32x4 acc[2][4];
    #pragma unroll
    for (int i = 0; i < 2; ++i)
        #pragma unroll
        for (int j = 0; j < 4; ++j) acc[i][j] = (f32x4){0.f, 0.f, 0.f, 0.f};

    for (int kb = k0; kb < k0 + klen; kb += 32) {
        *(u16x8*)&As[a_row][a_k] = pa;
        *(u16x8*)&Bs[b_row][b_k] = pb0;
        *(u16x8*)&Bs[b_row][b_k + 8] = pb1;
        __syncthreads();

        const int kn = kb + 32;
        if (kn < k0 + klen) {
            if (va) pa = *(const u16x8*)&A[abase + kn];
            if (vb) { pb0 = *(const u16x8*)&B[bbase + kn]; pb1 = *(const u16x8*)&B[bbase + kn + 8]; }
        }

        short8 af[2], bfr[4];
        #pragma unroll
        for (int i = 0; i < 2; ++i) af[i] = *(short8*)&As[wr * 32 + i * 16 + fr][kg * 8];
        #pragma unroll
        for (int j = 0; j < 4; ++j) bfr[j] = *(short8*)&Bs[wc * 64 + j * 16 + fr][kg * 8];
        #pragma unroll
        for (int i = 0; i < 2; ++i)
            #pragma unroll
            for (int j = 0; j < 4; ++j)
                acc[i][j] = __builtin_amdgcn_mfma_f32_16x16x32_bf16(af[i], bfr[j], acc[i][j], 0, 0, 0);
        __syncthreads();
    }

    const int orow0 = bx * 64 + wr * 32, ocol0 = n0 + wc * 64;
    if (Cbf) {
        unsigned short* Cw = Cbf + (size_t)blockIdx.z * M * N;
        #pragma unroll
        for (int i = 0; i < 2; ++i) {
            const int r0 = orow0 + i * 16 + kg * 4;
            #pragma unroll
            for (int j = 0; j < 4; ++j) {
                const int cc = ocol0 + j * 16 + fr;
                if (cc >= N) continue;
                #pragma unroll
                for (int r = 0; r < 4; ++r) {
                    const int rr = r0 + r;
                    if (rr < M) Cw[(size_t)rr * N + cc] = f2bf(acc[i][j][r]);
                }
            }
        }
    } else {
        float* Cw = C + (gridDim.z > 1 ? (size_t)blockIdx.z * M * N : 0);
        #pragma unroll
        for (int i = 0; i < 2; ++i) {
            const int r0 = orow0 + i * 16 + kg * 4;
            #pragma unroll
            for (int j = 0; j < 4; ++j) {
                const int cc = ocol0 + j * 16 + fr;
                if (cc >= N) continue;
                #pragma unroll
                for (int r = 0; r < 4; ++r) {
                    const int rr = r0 + r;
                    if (rr < M) Cw[(size_t)rr * N + cc] = acc[i][j][r];
                }
            }
        }
    }
}

// =============== K4: masked softmax + sparse attention (round-5-verified, verbatim) ===============
__global__ __launch_bounds__(256) void softmax_att_kernel(
    const float* __restrict__ sim, const float* __restrict__ attrs,
    unsigned short* __restrict__ att_outs)
{
    const int c = blockIdx.x, t = threadIdx.x;
    __shared__ float p_s[512];
    __shared__ float redm[4];
    __shared__ float reds[4];

    const float d0 = sim[(size_t)c * CLS + t];
    const float d1 = (t + 256 < CLS) ? sim[(size_t)c * CLS + t + 256] : NEGV;

    float vmax = fmaxf((d0 > THRESH_) ? d0 : NEGV, (d1 > THRESH_) ? d1 : NEGV);
    #pragma unroll
    for (int off = 32; off >= 1; off >>= 1) vmax = fmaxf(vmax, __shfl_down(vmax, off));
    const int wave = t >> 6, lane = t & 63;
    if (lane == 0) redm[wave] = vmax;
    __syncthreads();
    const float m = fmaxf(fmaxf(redm[0], redm[1]), fmaxf(redm[2], redm[3]));

    const float p0 = (d0 > THRESH_) ? expf(T_TEMP_ * (d0 - m)) : 0.f;
    const float p1 = (d1 > THRESH_) ? expf(T_TEMP_ * (d1 - m)) : 0.f;
    p_s[t] = p0;
    p_s[t + 256] = p1;
    float vsum = p0 + p1;
    #pragma unroll
    for (int off = 32; off >= 1; off >>= 1) vsum += __shfl_down(vsum, off);
    if (lane == 0) reds[wave] = vsum;
    __syncthreads();
    const float inv = 1.f / (reds[0] + reds[1] + reds[2] + reds[3]);

    float acc[4] = {0.f, 0.f, 0.f, 0.f};
    for (int base = 0; base < 512; base += 64) {
        const float pv_l = p_s[base + lane];
        unsigned long long mask = __ballot(pv_l > 0.f);
        while (mask) {
            const int l = __ffsll((long long)mask) - 1;
            mask &= mask - 1;
            const int c2 = base + l;
            const float pv = p_s[c2];
            const float* ar = &attrs[(size_t)c2 * 1024 + t];
            #pragma unroll
            for (int j = 0; j < 4; ++j) acc[j] += pv * ar[256 * j];
        }
    }
    #pragma unroll
    for (int j = 0; j < 4; ++j)
        att_outs[(size_t)c * 1024 + t + 256 * j] = f2bf(acc[j] * inv);
}

// =============== K5: hid partials (A1 imgf f32-inline / A2 atto bf16; B f32 inline) ===============
// grid (12, 8, 2): mt, nt, split (klen=512). Output bf16 hidP[2][756][1024].
__global__ __launch_bounds__(256) void hid_kernel(
    const float* __restrict__ imgf, const unsigned short* __restrict__ atto_bf,
    const float* __restrict__ imgw, const float* __restrict__ semw,
    unsigned short* __restrict__ hidP)
{
    __shared__ unsigned short As[64][40];
    __shared__ unsigned short Bs[128][40];
    const int t = threadIdx.x;
    const int mt = blockIdx.x, nt = blockIdx.y, split = blockIdx.z;
    const int n0 = nt * 128, k0 = split * 512;
    const bool img_side = (mt < 4);
    const int ar0 = img_side ? mt * 64 : (mt - 4) * 64;
    const int alim = img_side ? 256 : 500;
    const float* Bf = img_side ? imgw : semw;

    const int w = t >> 6, lane = t & 63;
    const int wr = w >> 1, wc = w & 1;
    const int fr = lane & 15, kg = lane >> 4;
    const int as_row = t >> 2, as_kq = t & 3;
    const int bs_nc = (t & 31) * 4, bs_kr = t >> 5;

    f32x4 acc[2][4];
    #pragma unroll
    for (int i = 0; i < 2; ++i)
        #pragma unroll
        for (int j = 0; j < 4; ++j) acc[i][j] = (f32x4){0.f, 0.f, 0.f, 0.f};

    for (int kb = k0; kb < k0 + 512; kb += 32) {
        {   // A stage (block-uniform branch)
            const int gr = ar0 + as_row;
            if (img_side) {
                float4 v0 = make_float4(0.f,0.f,0.f,0.f), v1 = v0;
                if (gr < alim) {
                    const float* ap = &imgf[(size_t)gr * 1024 + kb + as_kq * 8];
                    v0 = *(const float4*)ap; v1 = *(const float4*)(ap + 4);
                }
                *(u16x8*)&As[as_row][as_kq * 8] = pack8(v0, v1);
            } else {
                u16x8 pa = {0,0,0,0,0,0,0,0};
                if (gr < alim) pa = *(const u16x8*)&atto_bf[(size_t)gr * 1024 + kb + as_kq * 8];
                *(u16x8*)&As[as_row][as_kq * 8] = pa;
            }
        }
        {   // B stage: f32 [1024][1024] row-major -> Bs[n][k] (round-4-verified)
            const float* bp = &Bf[(size_t)(kb + bs_kr * 4) * 1024 + n0 + bs_nc];
            float4 r0 = *(const float4*)(bp);
            float4 r1 = *(const float4*)(bp + 1024);
            float4 r2 = *(const float4*)(bp + 2048);
            float4 r3 = *(const float4*)(bp + 3072);
            #pragma unroll
            for (int j = 0; j < 4; ++j) {
                unsigned int lo = (unsigned int)f2bf(fel(r0, j)) | ((unsigned int)f2bf(fel(r1, j)) << 16);
                unsigned int hi = (unsigned int)f2bf(fel(r2, j)) | ((unsigned int)f2bf(fel(r3, j)) << 16);
                uint2 u2; u2.x = lo; u2.y = hi;
                *(uint2*)&Bs[bs_nc + j][bs_kr * 4] = u2;
            }
        }
        __syncthreads();
        short8 af[2], bfr[4];
        #pragma unroll
        for (int i = 0; i < 2; ++i) af[i] = *(short8*)&As[wr * 32 + i * 16 + fr][kg * 8];
        #pragma unroll
        for (int j = 0; j < 4; ++j) bfr[j] = *(short8*)&Bs[wc * 64 + j * 16 + fr][kg * 8];
        #pragma unroll
        for (int i = 0; i < 2; ++i)
            #pragma unroll
            for (int j = 0; j < 4; ++j)
                acc[i][j] = __builtin_amdgcn_mfma_f32_16x16x32_bf16(af[i], bfr[j], acc[i][j], 0, 0, 0);
        __syncthreads();
    }

    // bf16 epilogue (round-5-verified): rows mt*64.. (imgf rows 0..255, atto rows 256..755)
    unsigned short* Cw = hidP + (size_t)split * (756 * 1024);
    const int orow0 = mt * 64 + wr * 32, ocol0 = n0 + wc * 64;
    #pragma unroll
    for (int i = 0; i < 2; ++i) {
        const int r0 = orow0 + i * 16 + kg * 4;
        #pragma unroll
        for (int j = 0; j < 4; ++j) {
            const int cc = ocol0 + j * 16 + fr;
            #pragma unroll
            for (int r = 0; r < 4; ++r) {
                const int rr = r0 + r;
                if (rr < 756) Cw[(size_t)rr * 1024 + cc] = f2bf(acc[i][j][r]);
            }
        }
    }
}

// =============== K6: fused relu-reduction + group finalize -> out ===============
// grid 256: bx=bid&3, by=(bid>>2)&7, bz=bid>>5 (h-chunk of 128). Partials via sc1
// stores; per-(bx,by) group of 8 syncs on a counter, then finalizes its 64x64 tile.
__global__ __launch_bounds__(256) void fused_kernel(
    const unsigned short* __restrict__ part, const float* __restrict__ sem_b,
    const float* __restrict__ fc_w, const float* __restrict__ fc_b,
    float* __restrict__ outP, float* __restrict__ out,
    unsigned int* __restrict__ cnt)
{
    __shared__ float imgs[64][68];
    __shared__ float sems[64][68];
    __shared__ float fcs[128];
    __shared__ unsigned int rank_s;
    const size_t pstride = (size_t)756 * 1024;
    const int t = threadIdx.x;
    const int bid = blockIdx.x;
    const int bx = bid & 3, by = (bid >> 2) & 7, bz = bid >> 5;
    const int b0 = bx * 64, c0 = by * 64, h0 = bz * 128;
    const int tb = t >> 4, tc = t & 15;

    if (t < 32) *(float4*)&fcs[t * 4] = *(const float4*)&fc_w[h0 + t * 4];

    f32x2 acc2[4][4];
    #pragma unroll
    for (int i = 0; i < 4; ++i)
        #pragma unroll
        for (int j = 0; j < 4; ++j) acc2[i][j] = (f32x2){0.f, 0.f};

    for (int hs = 0; hs < 2; ++hs) {
        const int hb = h0 + hs * 64;
        #pragma unroll
        for (int i = 0; i < 4; ++i) {
            const int row = (t >> 4) + 16 * i;
            const int col = (t & 15) * 4;
            f32x4 iv = {0.f, 0.f, 0.f, 0.f};
            const unsigned short* pi = &part[(size_t)(b0 + row) * 1024 + hb + col];
            #pragma unroll
            for (int z = 0; z < 2; ++z) {
                u16x4 vz = *(const u16x4*)(pi + (size_t)z * pstride);
                iv[0] += bf2f(vz[0]); iv[1] += bf2f(vz[1]);
                iv[2] += bf2f(vz[2]); iv[3] += bf2f(vz[3]);
            }
            *(f32x4*)&imgs[row][col] = iv;

            f32x4 sv = {0.f, 0.f, 0.f, 0.f};
            if (c0 + row < CLS) {
                const unsigned short* ps2 = &part[(size_t)(256 + c0 + row) * 1024 + hb + col];
                #pragma unroll
                for (int z = 0; z < 2; ++z) {
                    u16x4 vz = *(const u16x4*)(ps2 + (size_t)z * pstride);
                    sv[0] += bf2f(vz[0]); sv[1] += bf2f(vz[1]);
                    sv[2] += bf2f(vz[2]); sv[3] += bf2f(vz[3]);
                }
                const f32x4 bb = *(const f32x4*)&sem_b[hb + col];
                sv += bb;
            }
            *(f32x4*)&sems[row][col] = sv;
        }
        __syncthreads();

        #pragma unroll
        for (int h4 = 0; h4 < 16; ++h4) {
            f32x4 ia[4], sa[4];
            #pragma unroll
            for (int i = 0; i < 4; ++i) ia[i] = *(f32x4*)&imgs[tb + 16 * i][h4 * 4];
            #pragma unroll
            for (int j = 0; j < 4; ++j) sa[j] = *(f32x4*)&sems[tc + 16 * j][h4 * 4];
            const f32x4 wv = *(const f32x4*)&fcs[hs * 64 + h4 * 4];
            #pragma unroll
            for (int e2 = 0; e2 < 2; ++e2) {
                const f32x2 w2 = {wv[2 * e2], wv[2 * e2 + 1]};
                f32x2 ia2[4], sa2[4];
                #pragma unroll
                for (int i = 0; i < 4; ++i) ia2[i] = (f32x2){ia[i][2 * e2], ia[i][2 * e2 + 1]};
                #pragma unroll
                for (int j = 0; j < 4; ++j) sa2[j] = (f32x2){sa[j][2 * e2], sa[j][2 * e2 + 1]};
                #pragma unroll
                for (int i = 0; i < 4; ++i)
                    #pragma unroll
                    for (int j = 0; j < 4; ++j) {
                        f32x2 s = ia2[i] + sa2[j];
                        s = __builtin_elementwise_max(s, (f32x2){0.f, 0.f});
                        acc2[i][j] += s * w2;
                    }
            }
        }
        __syncthreads();
    }

    // sc1 partial stores
    #pragma unroll
    for (int i = 0; i < 4; ++i) {
        const int b = b0 + tb + 16 * i;
        #pragma unroll
        for (int j = 0; j < 4; ++j) {
            const int cc = c0 + tc + 16 * j;
            if (cc < CLS)
                __hip_atomic_store(&outP[((size_t)bz * BATCH + b) * CLS + cc],
                                   acc2[i][j][0] + acc2[i][j][1],
                                   __ATOMIC_RELAXED, __HIP_MEMORY_SCOPE_AGENT);
        }
    }
    asm volatile("s_waitcnt vmcnt(0)" ::: "memory");
    __syncthreads();
    const int g = bid & 31;
    if (t == 0) {
        rank_s = __hip_atomic_fetch_add(&cnt[g * 32], 1u, __ATOMIC_RELAXED,
                                        __HIP_MEMORY_SCOPE_AGENT);
        while (__hip_atomic_load(&cnt[g * 32], __ATOMIC_RELAXED,
                                 __HIP_MEMORY_SCOPE_AGENT) < 8u)
            __builtin_amdgcn_s_sleep(1);
    }
    __syncthreads();
    const int rank = (int)rank_s;   // 0..7
    const float bias = fc_b[0];
    #pragma unroll
    for (int pass = 0; pass < 2; ++pass) {
        const int row = b0 + rank * 8 + pass * 4 + (t >> 6);
        const int col = c0 + (t & 63);
        if (col < CLS) {
            float s = bias;
            #pragma unroll
            for (int z = 0; z < 8; ++z)
                s += outP[((size_t)z * BATCH + row) * CLS + col];
            out[(size_t)row * CLS + col] = s;
        }
    }
}

extern "C" void kernel_launch(void* const* d_in, const int* in_sizes, int n_in,
                              void* d_out, int out_size, void* d_ws, size_t ws_size,
                              hipStream_t stream)
{
    const float* imgf  = (const float*)d_in[0];
    const float* attrs = (const float*)d_in[1];
    const float* attg  = (const float*)d_in[3];
    const float* imgw  = (const float*)d_in[4];
    const float* semw  = (const float*)d_in[5];
    const float* semb  = (const float*)d_in[6];
    const float* fcw   = (const float*)d_in[7];
    const float* fcb   = (const float*)d_in[8];
    float* out = (float*)d_out;

    char* ws = (char*)d_ws;
    size_t off = 8192;   // counters: [0,4096) g-groups, [4096,8192) fused-groups
    auto alloc = [&](size_t b) { size_t o = off; off = (off + b + 255) & ~(size_t)255; return o; };
    unsigned int* cnt1 = (unsigned int*)ws;
    unsigned int* cnt2 = (unsigned int*)(ws + 4096);
    float* gpart          = (float*)(ws + alloc((size_t)8 * 512 * 256 * 4));
    unsigned short* gn_bf = (unsigned short*)(ws + alloc((size_t)500 * 256 * 2));
    float* sim            = (float*)(ws + alloc((size_t)CLS * CLS * 4));
    unsigned short* atto  = (unsigned short*)(ws + alloc((size_t)500 * 1024 * 2));
    unsigned short* hidP  = (unsigned short*)(ws + alloc((size_t)2 * 756 * 1024 * 2));
    float* outP           = (float*)(ws + alloc((size_t)8 * BATCH * CLS * 4));

    // reset group counters each call (captured into graph)
    hipMemsetAsync(d_ws, 0, 8192, stream);

    // K1: g GEMM (inline convert) + group reduce+norm -> gn_bf
    g_norm_kernel<<<128, 256, 0, stream>>>(attrs, attg, gpart, gn_bf, cnt1);

    // K3: sim = gn @ gn^T [500,500]
    mfma_gemm_bf<<<dim3(8, 4, 1), 256, 0, stream>>>(
        gn_bf, 500, gn_bf, 1000, 500, gn_bf, gn_bf,
        sim, nullptr, 500, 500, 256, 256);

    // K4: masked softmax + sparse accumulate -> atto (bf16)
    softmax_att_kernel<<<CLS, 256, 0, stream>>>(sim, attrs, atto);

    // K5: hid partials [2][756][1024] bf16
    hid_kernel<<<dim3(12, 8, 2), 256, 0, stream>>>(imgf, atto, imgw, semw, hidP);

    // K6: fused relu-reduction + group finalize -> out
    fused_kernel<<<256, 256, 0, stream>>>(hidP, semb, fcw, fcb, outP, out, cnt2);
}

// Round 11
// 68.538 us; speedup vs baseline: 5.0269x; 1.0914x over previous
//
#include <hip/hip_runtime.h>
#include <math.h>

#define BATCH 256
#define CLS 500
#define T_TEMP_ 10.0f
#define THRESH_ 0.86602540378443864676f
#define NEGV -9.0e15f

typedef __attribute__((ext_vector_type(8))) short short8;
typedef __attribute__((ext_vector_type(8))) unsigned short u16x8;
typedef __attribute__((ext_vector_type(4))) unsigned short u16x4;
typedef __attribute__((ext_vector_type(4))) float f32x4;
typedef __attribute__((ext_vector_type(2))) float f32x2;

static __device__ __forceinline__ unsigned short f2bf(float x) {
    unsigned int u = __builtin_bit_cast(unsigned int, x);
    u += 0x7fff + ((u >> 16) & 1);
    return (unsigned short)(u >> 16);
}
static __device__ __forceinline__ float bf2f(unsigned short v) {
    return __builtin_bit_cast(float, (unsigned int)v << 16);
}
static __device__ __forceinline__ float fel(const float4& v, int j) { return (&v.x)[j]; }
static __device__ __forceinline__ u16x8 pack8(const float4& a, const float4& b) {
    u16x8 o;
    o[0] = f2bf(a.x); o[1] = f2bf(a.y); o[2] = f2bf(a.z); o[3] = f2bf(a.w);
    o[4] = f2bf(b.x); o[5] = f2bf(b.y); o[6] = f2bf(b.z); o[7] = f2bf(b.w);
    return o;
}

// =============== K1: gpart[8][512][256] = split-K partials of g = attrs @ att_g ===============
// grid 128: mt = bid>>4 (8), nt = (bid>>3)&1, split = bid&7 (klen=128).
// Inline f32->bf16 staging (r9-verified); plain f32 stores (r6-verified pattern).
__global__ __launch_bounds__(256) void gpart_kernel(
    const float* __restrict__ attrs, const float* __restrict__ attg,
    float* __restrict__ gpart)
{
    __shared__ unsigned short As[64][40];
    __shared__ unsigned short Bs[128][40];
    const int t = threadIdx.x;
    const int bid = blockIdx.x;
    const int mt = bid >> 4, nt = (bid >> 3) & 1, split = bid & 7;
    const int n0 = nt * 128, ar0 = mt * 64, k0 = split * 128;

    const int w = t >> 6, lane = t & 63;
    const int wr = w >> 1, wc = w & 1;
    const int fr = lane & 15, kg = lane >> 4;
    const int as_row = t >> 2, as_kq = t & 3;
    const int bs_nc = (t & 31) * 4, bs_kr = t >> 5;

    f32x4 acc[2][4];
    #pragma unroll
    for (int i = 0; i < 2; ++i)
        #pragma unroll
        for (int j = 0; j < 4; ++j) acc[i][j] = (f32x4){0.f, 0.f, 0.f, 0.f};

    for (int kb = k0; kb < k0 + 128; kb += 32) {
        {   // A stage: attrs f32 -> bf16
            const int gr = ar0 + as_row;
            float4 v0 = make_float4(0.f,0.f,0.f,0.f), v1 = v0;
            if (gr < CLS) {
                const float* ap = &attrs[(size_t)gr * 1024 + kb + as_kq * 8];
                v0 = *(const float4*)ap; v1 = *(const float4*)(ap + 4);
            }
            *(u16x8*)&As[as_row][as_kq * 8] = pack8(v0, v1);
        }
        {   // B stage: attg f32 [1024][256] row-major -> Bs[n][k]
            const float* bp = &attg[(size_t)(kb + bs_kr * 4) * 256 + n0 + bs_nc];
            float4 r0 = *(const float4*)(bp);
            float4 r1 = *(const float4*)(bp + 256);
            float4 r2 = *(const float4*)(bp + 512);
            float4 r3 = *(const float4*)(bp + 768);
            #pragma unroll
            for (int j = 0; j < 4; ++j) {
                unsigned int lo = (unsigned int)f2bf(fel(r0, j)) | ((unsigned int)f2bf(fel(r1, j)) << 16);
                unsigned int hi = (unsigned int)f2bf(fel(r2, j)) | ((unsigned int)f2bf(fel(r3, j)) << 16);
                uint2 u2; u2.x = lo; u2.y = hi;
                *(uint2*)&Bs[bs_nc + j][bs_kr * 4] = u2;
            }
        }
        __syncthreads();
        short8 af[2], bfr[4];
        #pragma unroll
        for (int i = 0; i < 2; ++i) af[i] = *(short8*)&As[wr * 32 + i * 16 + fr][kg * 8];
        #pragma unroll
        for (int j = 0; j < 4; ++j) bfr[j] = *(short8*)&Bs[wc * 64 + j * 16 + fr][kg * 8];
        #pragma unroll
        for (int i = 0; i < 2; ++i)
            #pragma unroll
            for (int j = 0; j < 4; ++j)
                acc[i][j] = __builtin_amdgcn_mfma_f32_16x16x32_bf16(af[i], bfr[j], acc[i][j], 0, 0, 0);
        __syncthreads();
    }

    float* Gp = gpart + (size_t)split * (512 * 256);
    const int orow0 = ar0 + wr * 32, ocol0 = n0 + wc * 64;
    #pragma unroll
    for (int i = 0; i < 2; ++i) {
        const int r0 = orow0 + i * 16 + kg * 4;
        #pragma unroll
        for (int j = 0; j < 4; ++j) {
            const int cc = ocol0 + j * 16 + fr;
            #pragma unroll
            for (int r = 0; r < 4; ++r)
                Gp[(size_t)(r0 + r) * 256 + cc] = acc[i][j][r];
        }
    }
}

// =============== K2: reduce 8 partials + row-normalize -> gn bf16 (r6-verified body) ===============
__global__ __launch_bounds__(256) void reduce_norm_kernel(
    const float* __restrict__ part, unsigned short* __restrict__ gn_bf)
{
    const int c = blockIdx.x, t = threadIdx.x;
    float v = 0.f;
    #pragma unroll
    for (int z = 0; z < 8; ++z) v += part[(size_t)z * (512 * 256) + c * 256 + t];
    float ss = v * v;
    #pragma unroll
    for (int off = 32; off >= 1; off >>= 1) ss += __shfl_down(ss, off);
    __shared__ float red[4];
    const int wave = t >> 6, lane = t & 63;
    if (lane == 0) red[wave] = ss;
    __syncthreads();
    const float tot = red[0] + red[1] + red[2] + red[3];
    const float rn  = 1.f / sqrtf(tot);
    gn_bf[c * 256 + t] = f2bf(v * rn);
}

// =============== K3: sim = gn @ gn^T (r6-verified mfma_gemm_bf, verbatim) ===============
__global__ __launch_bounds__(256) void mfma_gemm_bf(
    const unsigned short* __restrict__ A1, int alim1,
    const unsigned short* __restrict__ A2, int a2t0, int alim2,
    const unsigned short* __restrict__ B1, const unsigned short* __restrict__ B2,
    float* __restrict__ C, unsigned short* __restrict__ Cbf,
    int M, int N, int K, int klen)
{
    __shared__ unsigned short As[64][40];
    __shared__ unsigned short Bs[128][40];

    const int t  = threadIdx.x;
    const int bx = blockIdx.x;
    const int n0 = blockIdx.y * 128;
    const int k0 = blockIdx.z * klen;

    const unsigned short* A; const unsigned short* B; int ar0, alim;
    if (bx < a2t0) { A = A1; B = B1; ar0 = bx * 64;          alim = alim1; }
    else           { A = A2; B = B2; ar0 = (bx - a2t0) * 64; alim = alim2; }

    const int w = t >> 6, lane = t & 63;
    const int wr = w >> 1, wc = w & 1;
    const int fr = lane & 15, kg = lane >> 4;

    const int a_row = t >> 2, a_k = (t & 3) * 8;
    const int b_row = t >> 1, b_k = (t & 1) * 16;
    const int gra = ar0 + a_row;
    const int grb = n0 + b_row;
    const bool va = gra < alim;
    const bool vb = grb < N;
    const size_t abase = (size_t)gra * K + a_k;
    const size_t bbase = (size_t)grb * K + b_k;

    u16x8 zz = {0,0,0,0,0,0,0,0};
    u16x8 pa = zz, pb0 = zz, pb1 = zz;
    if (va) pa = *(const u16x8*)&A[abase + k0];
    if (vb) { pb0 = *(const u16x8*)&B[bbase + k0]; pb1 = *(const u16x8*)&B[bbase + k0 + 8]; }

    f32x4 acc[2][4];
    #pragma unroll
    for (int i = 0; i < 2; ++i)
        #pragma unroll
        for (int j = 0; j < 4; ++j) acc[i][j] = (f32x4){0.f, 0.f, 0.f, 0.f};

    for (int kb = k0; kb < k0 + klen; kb += 32) {
        *(u16x8*)&As[a_row][a_k] = pa;
        *(u16x8*)&Bs[b_row][b_k] = pb0;
        *(u16x8*)&Bs[b_row][b_k + 8] = pb1;
        __syncthreads();

        const int kn = kb + 32;
        if (kn < k0 + klen) {
            if (va) pa = *(const u16x8*)&A[abase + kn];
            if (vb) { pb0 = *(const u16x8*)&B[bbase + kn]; pb1 = *(const u16x8*)&B[bbase + kn + 8]; }
        }

        short8 af[2], bfr[4];
        #pragma unroll
        for (int i = 0; i < 2; ++i) af[i] = *(short8*)&As[wr * 32 + i * 16 + fr][kg * 8];
        #pragma unroll
        for (int j = 0; j < 4; ++j) bfr[j] = *(short8*)&Bs[wc * 64 + j * 16 + fr][kg * 8];
        #pragma unroll
        for (int i = 0; i < 2; ++i)
            #pragma unroll
            for (int j = 0; j < 4; ++j)
                acc[i][j] = __builtin_amdgcn_mfma_f32_16x16x32_bf16(af[i], bfr[j], acc[i][j], 0, 0, 0);
        __syncthreads();
    }

    const int orow0 = bx * 64 + wr * 32, ocol0 = n0 + wc * 64;
    if (Cbf) {
        unsigned short* Cw = Cbf + (size_t)blockIdx.z * M * N;
        #pragma unroll
        for (int i = 0; i < 2; ++i) {
            const int r0 = orow0 + i * 16 + kg * 4;
            #pragma unroll
            for (int j = 0; j < 4; ++j) {
                const int cc = ocol0 + j * 16 + fr;
                if (cc >= N) continue;
                #pragma unroll
                for (int r = 0; r < 4; ++r) {
                    const int rr = r0 + r;
                    if (rr < M) Cw[(size_t)rr * N + cc] = f2bf(acc[i][j][r]);
                }
            }
        }
    } else {
        float* Cw = C + (gridDim.z > 1 ? (size_t)blockIdx.z * M * N : 0);
        #pragma unroll
        for (int i = 0; i < 2; ++i) {
            const int r0 = orow0 + i * 16 + kg * 4;
            #pragma unroll
            for (int j = 0; j < 4; ++j) {
                const int cc = ocol0 + j * 16 + fr;
                if (cc >= N) continue;
                #pragma unroll
                for (int r = 0; r < 4; ++r) {
                    const int rr = r0 + r;
                    if (rr < M) Cw[(size_t)rr * N + cc] = acc[i][j][r];
                }
            }
        }
    }
}

// =============== K4: masked softmax + sparse attention (r6-verified, verbatim) ===============
__global__ __launch_bounds__(256) void softmax_att_kernel(
    const float* __restrict__ sim, const float* __restrict__ attrs,
    unsigned short* __restrict__ att_outs)
{
    const int c = blockIdx.x, t = threadIdx.x;
    __shared__ float p_s[512];
    __shared__ float redm[4];
    __shared__ float reds[4];

    const float d0 = sim[(size_t)c * CLS + t];
    const float d1 = (t + 256 < CLS) ? sim[(size_t)c * CLS + t + 256] : NEGV;

    float vmax = fmaxf((d0 > THRESH_) ? d0 : NEGV, (d1 > THRESH_) ? d1 : NEGV);
    #pragma unroll
    for (int off = 32; off >= 1; off >>= 1) vmax = fmaxf(vmax, __shfl_down(vmax, off));
    const int wave = t >> 6, lane = t & 63;
    if (lane == 0) redm[wave] = vmax;
    __syncthreads();
    const float m = fmaxf(fmaxf(redm[0], redm[1]), fmaxf(redm[2], redm[3]));

    const float p0 = (d0 > THRESH_) ? expf(T_TEMP_ * (d0 - m)) : 0.f;
    const float p1 = (d1 > THRESH_) ? expf(T_TEMP_ * (d1 - m)) : 0.f;
    p_s[t] = p0;
    p_s[t + 256] = p1;
    float vsum = p0 + p1;
    #pragma unroll
    for (int off = 32; off >= 1; off >>= 1) vsum += __shfl_down(vsum, off);
    if (lane == 0) reds[wave] = vsum;
    __syncthreads();
    const float inv = 1.f / (reds[0] + reds[1] + reds[2] + reds[3]);

    float acc[4] = {0.f, 0.f, 0.f, 0.f};
    for (int base = 0; base < 512; base += 64) {
        const float pv_l = p_s[base + lane];
        unsigned long long mask = __ballot(pv_l > 0.f);
        while (mask) {
            const int l = __ffsll((long long)mask) - 1;
            mask &= mask - 1;
            const int c2 = base + l;
            const float pv = p_s[c2];
            const float* ar = &attrs[(size_t)c2 * 1024 + t];
            #pragma unroll
            for (int j = 0; j < 4; ++j) acc[j] += pv * ar[256 * j];
        }
    }
    #pragma unroll
    for (int j = 0; j < 4; ++j)
        att_outs[(size_t)c * 1024 + t + 256 * j] = f2bf(acc[j] * inv);
}

// =============== K5: hid partials (r9-verified, verbatim) ===============
__global__ __launch_bounds__(256) void hid_kernel(
    const float* __restrict__ imgf, const unsigned short* __restrict__ atto_bf,
    const float* __restrict__ imgw, const float* __restrict__ semw,
    unsigned short* __restrict__ hidP)
{
    __shared__ unsigned short As[64][40];
    __shared__ unsigned short Bs[128][40];
    const int t = threadIdx.x;
    const int mt = blockIdx.x, nt = blockIdx.y, split = blockIdx.z;
    const int n0 = nt * 128, k0 = split * 512;
    const bool img_side = (mt < 4);
    const int ar0 = img_side ? mt * 64 : (mt - 4) * 64;
    const int alim = img_side ? 256 : 500;
    const float* Bf = img_side ? imgw : semw;

    const int w = t >> 6, lane = t & 63;
    const int wr = w >> 1, wc = w & 1;
    const int fr = lane & 15, kg = lane >> 4;
    const int as_row = t >> 2, as_kq = t & 3;
    const int bs_nc = (t & 31) * 4, bs_kr = t >> 5;

    f32x4 acc[2][4];
    #pragma unroll
    for (int i = 0; i < 2; ++i)
        #pragma unroll
        for (int j = 0; j < 4; ++j) acc[i][j] = (f32x4){0.f, 0.f, 0.f, 0.f};

    for (int kb = k0; kb < k0 + 512; kb += 32) {
        {
            const int gr = ar0 + as_row;
            if (img_side) {
                float4 v0 = make_float4(0.f,0.f,0.f,0.f), v1 = v0;
                if (gr < alim) {
                    const float* ap = &imgf[(size_t)gr * 1024 + kb + as_kq * 8];
                    v0 = *(const float4*)ap; v1 = *(const float4*)(ap + 4);
                }
                *(u16x8*)&As[as_row][as_kq * 8] = pack8(v0, v1);
            } else {
                u16x8 pa = {0,0,0,0,0,0,0,0};
                if (gr < alim) pa = *(const u16x8*)&atto_bf[(size_t)gr * 1024 + kb + as_kq * 8];
                *(u16x8*)&As[as_row][as_kq * 8] = pa;
            }
        }
        {
            const float* bp = &Bf[(size_t)(kb + bs_kr * 4) * 1024 + n0 + bs_nc];
            float4 r0 = *(const float4*)(bp);
            float4 r1 = *(const float4*)(bp + 1024);
            float4 r2 = *(const float4*)(bp + 2048);
            float4 r3 = *(const float4*)(bp + 3072);
            #pragma unroll
            for (int j = 0; j < 4; ++j) {
                unsigned int lo = (unsigned int)f2bf(fel(r0, j)) | ((unsigned int)f2bf(fel(r1, j)) << 16);
                unsigned int hi = (unsigned int)f2bf(fel(r2, j)) | ((unsigned int)f2bf(fel(r3, j)) << 16);
                uint2 u2; u2.x = lo; u2.y = hi;
                *(uint2*)&Bs[bs_nc + j][bs_kr * 4] = u2;
            }
        }
        __syncthreads();
        short8 af[2], bfr[4];
        #pragma unroll
        for (int i = 0; i < 2; ++i) af[i] = *(short8*)&As[wr * 32 + i * 16 + fr][kg * 8];
        #pragma unroll
        for (int j = 0; j < 4; ++j) bfr[j] = *(short8*)&Bs[wc * 64 + j * 16 + fr][kg * 8];
        #pragma unroll
        for (int i = 0; i < 2; ++i)
            #pragma unroll
            for (int j = 0; j < 4; ++j)
                acc[i][j] = __builtin_amdgcn_mfma_f32_16x16x32_bf16(af[i], bfr[j], acc[i][j], 0, 0, 0);
        __syncthreads();
    }

    unsigned short* Cw = hidP + (size_t)split * (756 * 1024);
    const int orow0 = mt * 64 + wr * 32, ocol0 = n0 + wc * 64;
    #pragma unroll
    for (int i = 0; i < 2; ++i) {
        const int r0 = orow0 + i * 16 + kg * 4;
        #pragma unroll
        for (int j = 0; j < 4; ++j) {
            const int cc = ocol0 + j * 16 + fr;
            #pragma unroll
            for (int r = 0; r < 4; ++r) {
                const int rr = r0 + r;
                if (rr < 756) Cw[(size_t)rr * 1024 + cc] = f2bf(acc[i][j][r]);
            }
        }
    }
}

// =============== K6: fused relu-reduction (r6-verified body, 2 bf16 partials) ===============
__global__ __launch_bounds__(256) void fused_out_partial(
    const unsigned short* __restrict__ part, const float* __restrict__ sem_b,
    const float* __restrict__ fc_w, float* __restrict__ outpart)
{
    __shared__ float imgs[64][68];
    __shared__ float sems[64][68];
    __shared__ float fcs[128];

    const size_t pstride = (size_t)756 * 1024;
    const int t  = threadIdx.x;
    const int tb = t >> 4, tc = t & 15;
    const int b0 = blockIdx.x * 64, c0 = blockIdx.y * 64;
    const int h0 = blockIdx.z * 128;

    if (t < 32) *(float4*)&fcs[t * 4] = *(const float4*)&fc_w[h0 + t * 4];

    f32x2 acc2[4][4];
    #pragma unroll
    for (int i = 0; i < 4; ++i)
        #pragma unroll
        for (int j = 0; j < 4; ++j) acc2[i][j] = (f32x2){0.f, 0.f};

    for (int hs = 0; hs < 2; ++hs) {
        const int hb = h0 + hs * 64;
        #pragma unroll
        for (int i = 0; i < 4; ++i) {
            const int row = (t >> 4) + 16 * i;
            const int col = (t & 15) * 4;
            f32x4 iv = {0.f, 0.f, 0.f, 0.f};
            const unsigned short* pi = &part[(size_t)(b0 + row) * 1024 + hb + col];
            #pragma unroll
            for (int z = 0; z < 2; ++z) {
                u16x4 vz = *(const u16x4*)(pi + (size_t)z * pstride);
                iv[0] += bf2f(vz[0]); iv[1] += bf2f(vz[1]);
                iv[2] += bf2f(vz[2]); iv[3] += bf2f(vz[3]);
            }
            *(f32x4*)&imgs[row][col] = iv;

            f32x4 sv = {0.f, 0.f, 0.f, 0.f};
            if (c0 + row < CLS) {
                const unsigned short* ps2 = &part[(size_t)(256 + c0 + row) * 1024 + hb + col];
                #pragma unroll
                for (int z = 0; z < 2; ++z) {
                    u16x4 vz = *(const u16x4*)(ps2 + (size_t)z * pstride);
                    sv[0] += bf2f(vz[0]); sv[1] += bf2f(vz[1]);
                    sv[2] += bf2f(vz[2]); sv[3] += bf2f(vz[3]);
                }
                const f32x4 bb = *(const f32x4*)&sem_b[hb + col];
                sv += bb;
            }
            *(f32x4*)&sems[row][col] = sv;
        }
        __syncthreads();

        #pragma unroll
        for (int h4 = 0; h4 < 16; ++h4) {
            f32x4 ia[4], sa[4];
            #pragma unroll
            for (int i = 0; i < 4; ++i) ia[i] = *(f32x4*)&imgs[tb + 16 * i][h4 * 4];
            #pragma unroll
            for (int j = 0; j < 4; ++j) sa[j] = *(f32x4*)&sems[tc + 16 * j][h4 * 4];
            const f32x4 wv = *(const f32x4*)&fcs[hs * 64 + h4 * 4];
            #pragma unroll
            for (int e2 = 0; e2 < 2; ++e2) {
                const f32x2 w2 = {wv[2 * e2], wv[2 * e2 + 1]};
                f32x2 ia2[4], sa2[4];
                #pragma unroll
                for (int i = 0; i < 4; ++i) ia2[i] = (f32x2){ia[i][2 * e2], ia[i][2 * e2 + 1]};
                #pragma unroll
                for (int j = 0; j < 4; ++j) sa2[j] = (f32x2){sa[j][2 * e2], sa[j][2 * e2 + 1]};
                #pragma unroll
                for (int i = 0; i < 4; ++i)
                    #pragma unroll
                    for (int j = 0; j < 4; ++j) {
                        f32x2 s = ia2[i] + sa2[j];
                        s = __builtin_elementwise_max(s, (f32x2){0.f, 0.f});
                        acc2[i][j] += s * w2;
                    }
            }
        }
        __syncthreads();
    }

    const int nh = blockIdx.z;
    #pragma unroll
    for (int i = 0; i < 4; ++i) {
        const int b = b0 + tb + 16 * i;
        #pragma unroll
        for (int j = 0; j < 4; ++j) {
            const int cc = c0 + tc + 16 * j;
            if (cc < CLS)
                outpart[((size_t)nh * BATCH + b) * CLS + cc] = acc2[i][j][0] + acc2[i][j][1];
        }
    }
}

// =============== K7: finalize (r6-verified, verbatim) ===============
__global__ __launch_bounds__(256) void finalize_kernel(
    const float* __restrict__ partial, const float* __restrict__ fc_b,
    float* __restrict__ out)
{
    const int idx = blockIdx.x * 256 + threadIdx.x;
    if (idx >= BATCH * CLS) return;
    float s = fc_b[0];
    #pragma unroll
    for (int nh = 0; nh < 8; ++nh)
        s += partial[(size_t)nh * (BATCH * CLS) + idx];
    out[idx] = s;
}

extern "C" void kernel_launch(void* const* d_in, const int* in_sizes, int n_in,
                              void* d_out, int out_size, void* d_ws, size_t ws_size,
                              hipStream_t stream)
{
    const float* imgf  = (const float*)d_in[0];
    const float* attrs = (const float*)d_in[1];
    const float* attg  = (const float*)d_in[3];
    const float* imgw  = (const float*)d_in[4];
    const float* semw  = (const float*)d_in[5];
    const float* semb  = (const float*)d_in[6];
    const float* fcw   = (const float*)d_in[7];
    const float* fcb   = (const float*)d_in[8];
    float* out = (float*)d_out;

    char* ws = (char*)d_ws;
    size_t off = 0;
    auto alloc = [&](size_t b) { size_t o = off; off = (off + b + 255) & ~(size_t)255; return o; };
    float* gpart          = (float*)(ws + alloc((size_t)8 * 512 * 256 * 4));    // 4.19 MB
    unsigned short* gn_bf = (unsigned short*)(ws + alloc((size_t)500 * 256 * 2));
    float* sim            = (float*)(ws + alloc((size_t)CLS * CLS * 4));        // 1 MB
    unsigned short* atto  = (unsigned short*)(ws + alloc((size_t)500 * 1024 * 2));
    unsigned short* hidP  = (unsigned short*)(ws + alloc((size_t)2 * 756 * 1024 * 2));
    float* outP           = (float*)(ws + alloc((size_t)8 * BATCH * CLS * 4));

    // K1: g split-K partials (inline convert)
    gpart_kernel<<<128, 256, 0, stream>>>(attrs, attg, gpart);
    // K2: reduce 8 partials + row-normalize -> gn bf16
    reduce_norm_kernel<<<CLS, 256, 0, stream>>>(gpart, gn_bf);
    // K3: sim = gn @ gn^T [500,500] f32
    mfma_gemm_bf<<<dim3(8, 4, 1), 256, 0, stream>>>(
        gn_bf, 500, gn_bf, 1000, 500, gn_bf, gn_bf,
        sim, nullptr, 500, 500, 256, 256);
    // K4: masked softmax + sparse accumulate -> atto bf16
    softmax_att_kernel<<<CLS, 256, 0, stream>>>(sim, attrs, atto);
    // K5: hid partials [2][756][1024] bf16 (inline convert)
    hid_kernel<<<dim3(12, 8, 2), 256, 0, stream>>>(imgf, atto, imgw, semw, hidP);
    // K6: fused relu-reduction -> outP[8][256][500]
    fused_out_partial<<<dim3(4, 8, 8), 256, 0, stream>>>(hidP, semb, fcw, outP);
    // K7: finalize
    finalize_kernel<<<(BATCH * CLS + 255) / 256, 256, 0, stream>>>(outP, fcb, out);
}